// Round 6
// baseline (192.073 us; speedup 1.0000x reference)
//
#include <hip/hip_runtime.h>

// GAT, round 5: fix of round-4 sort/scan algorithm (crash was the k_i==1024
// bucket: stale LDS cursor -> iol OOB -> garbage row index -> out OOB fault).
// e_ij = leaky(s1_i + s2_j) is rank-1 + monotone kink: sorting j by s2
// makes each row's negative-branch set a PREFIX. Then
//   out_i = c1_i*(U_N - U_{k_i}) + c2_i*V_{k_i},
//   U_r = sum_{r'<r} exp(s2_sorted)*h[jmap], V_r = same with exp(alpha*s2),
//   k_i = #{j: s2_j < -s1_i},  c1 = exp(s1-m)/Z, c2 = exp(a*s1-m)/Z.
// O(N^2 F) GEMM -> O(N F) streaming scan.

typedef unsigned short u16;
typedef unsigned int   u32;
typedef float  f32x4  __attribute__((ext_vector_type(4)));
typedef __bf16 bf16x8 __attribute__((ext_vector_type(8)));
typedef __bf16 bf16x4 __attribute__((ext_vector_type(4)));

#define NB    64
#define NENT  1024
#define FD    256
#define NROWS (NB * NENT)
#define ALPHA 0.2f

typedef __attribute__((address_space(1))) const void* gas_ptr;
typedef __attribute__((address_space(3))) void*       las_ptr;
__device__ __forceinline__ void gload16(const void* g, void* l) {
  __builtin_amdgcn_global_load_lds((gas_ptr)g, (las_ptr)l, 16, 0, 0);
}

// ---------------- k_wa: Wa1 = W@a1, Wa2 = W@a2 (fp32 exact) ----------------
__global__ __launch_bounds__(256) void k_wa(const float* __restrict__ W,
                                            const float* __restrict__ a,
                                            float* __restrict__ Wa1,
                                            float* __restrict__ Wa2) {
  const int k = blockIdx.x, f = threadIdx.x;
  const float w = W[(size_t)k * FD + f];
  float p1 = w * a[f];
  float p2 = w * a[FD + f];
#pragma unroll
  for (int off = 1; off < 64; off <<= 1) {
    p1 += __shfl_xor(p1, off, 64);
    p2 += __shfl_xor(p2, off, 64);
  }
  __shared__ float r1[4], r2[4];
  const int wv = f >> 6, lane = f & 63;
  if (lane == 0) { r1[wv] = p1; r2[wv] = p2; }
  __syncthreads();
  if (f == 0) {
    Wa1[k] = r1[0] + r1[1] + r1[2] + r1[3];
    Wa2[k] = r2[0] + r2[1] + r2[2] + r2[3];
  }
}

// ---------------- k_wt: Wt[f][k] = bf16(W[k][f]) ----------------
__global__ __launch_bounds__(256) void k_wt(const float* __restrict__ W,
                                            u16* __restrict__ Wt) {
  __shared__ float tile[64][65];
  const int t = threadIdx.x;
  const int ki = blockIdx.x >> 2, fi = blockIdx.x & 3;
  const int k0 = ki * 64, f0 = fi * 64;
  const int r = t >> 4, c4 = (t & 15) * 4;
#pragma unroll
  for (int it = 0; it < 4; ++it) {
    const int row = r + it * 16;
    float4 v = *(const float4*)&W[(size_t)(k0 + row) * FD + f0 + c4];
    tile[row][c4 + 0] = v.x; tile[row][c4 + 1] = v.y;
    tile[row][c4 + 2] = v.z; tile[row][c4 + 3] = v.w;
  }
  __syncthreads();
#pragma unroll
  for (int it = 0; it < 4; ++it) {
    const int fr = r + it * 16;
    bf16x4 pk;
    pk[0] = (__bf16)tile[c4 + 0][fr]; pk[1] = (__bf16)tile[c4 + 1][fr];
    pk[2] = (__bf16)tile[c4 + 2][fr]; pk[3] = (__bf16)tile[c4 + 3][fr];
    *(bf16x4*)&Wt[(size_t)(f0 + fr) * FD + k0 + c4] = pk;
  }
}

// -------- k_h: h = bf16(x@W) row-major, s1, s2 (256x256 tile, dbuf) --------
__global__ __launch_bounds__(512, 2) void k_h(
    const float* __restrict__ x, const u16* __restrict__ Wt,
    const float* __restrict__ Wa1g, const float* __restrict__ Wa2g,
    u16* __restrict__ h, float* __restrict__ s1, float* __restrict__ s2) {
  __shared__ __align__(16) char smem[67584];
  u16* Ab = (u16*)smem;                    // [2][4][256][8] = 32 KB
  u16* Bb = (u16*)(smem + 32768);          // [2][4][256][8] = 32 KB
  float* wa1 = (float*)(smem + 65536);
  float* wa2 = wa1 + FD;
  const int t = threadIdx.x;
  const int lane = t & 63, wv = t >> 6;
  const int wr = wv >> 2, wc = wv & 3;          // wave tile 128x64
  const int g16 = lane >> 4, c15 = lane & 15;
  const int p = blockIdx.x;
  const int lb = (p & 7) * 32 + (p >> 3);       // XCD-chunked
  const int rT = lb * 256;
  if (t < FD) { wa1[t] = Wa1g[t]; wa2[t] = Wa2g[t]; }
  const int row = t >> 1, half = t & 1;         // staging: 2 thr/row, 16 k
  const float* xsrc = x + (size_t)(rT + row) * FD + half * 16;
  float p1 = 0.f, p2 = 0.f;
  f32x4 acc[8][4];
  const f32x4 vz = {0.f, 0.f, 0.f, 0.f};
#pragma unroll
  for (int i = 0; i < 8; ++i)
#pragma unroll
    for (int j = 0; j < 4; ++j) acc[i][j] = vz;

  auto stage = [&](int nb, int kc, const float4& f0, const float4& f1,
                   const float4& f2, const float4& f3) {
    const int k0n = kc * 32;
    const int d0 = t;
    gload16(Wt + (size_t)(d0 & 255) * FD + k0n + (d0 >> 8) * 8,
            (char*)Bb + nb * 8192 * 2 + d0 * 16);
    const int d1 = t + 512;
    gload16(Wt + (size_t)(d1 & 255) * FD + k0n + (d1 >> 8) * 8,
            (char*)Bb + nb * 8192 * 2 + d1 * 16);
    bf16x8 w0, w1;
    w0[0] = (__bf16)f0.x; w0[1] = (__bf16)f0.y;
    w0[2] = (__bf16)f0.z; w0[3] = (__bf16)f0.w;
    w0[4] = (__bf16)f1.x; w0[5] = (__bf16)f1.y;
    w0[6] = (__bf16)f1.z; w0[7] = (__bf16)f1.w;
    w1[0] = (__bf16)f2.x; w1[1] = (__bf16)f2.y;
    w1[2] = (__bf16)f2.z; w1[3] = (__bf16)f2.w;
    w1[4] = (__bf16)f3.x; w1[5] = (__bf16)f3.y;
    w1[6] = (__bf16)f3.z; w1[7] = (__bf16)f3.w;
    *(bf16x8*)(Ab + ((nb * 4 + half * 2) * 256 + row) * 8) = w0;
    *(bf16x8*)(Ab + ((nb * 4 + half * 2 + 1) * 256 + row) * 8) = w1;
    const int kb = k0n + half * 16;
    p1 += f0.x*wa1[kb+ 0] + f0.y*wa1[kb+ 1] + f0.z*wa1[kb+ 2] + f0.w*wa1[kb+ 3]
        + f1.x*wa1[kb+ 4] + f1.y*wa1[kb+ 5] + f1.z*wa1[kb+ 6] + f1.w*wa1[kb+ 7]
        + f2.x*wa1[kb+ 8] + f2.y*wa1[kb+ 9] + f2.z*wa1[kb+10] + f2.w*wa1[kb+11]
        + f3.x*wa1[kb+12] + f3.y*wa1[kb+13] + f3.z*wa1[kb+14] + f3.w*wa1[kb+15];
    p2 += f0.x*wa2[kb+ 0] + f0.y*wa2[kb+ 1] + f0.z*wa2[kb+ 2] + f0.w*wa2[kb+ 3]
        + f1.x*wa2[kb+ 4] + f1.y*wa2[kb+ 5] + f1.z*wa2[kb+ 6] + f1.w*wa2[kb+ 7]
        + f2.x*wa2[kb+ 8] + f2.y*wa2[kb+ 9] + f2.z*wa2[kb+10] + f2.w*wa2[kb+11]
        + f3.x*wa2[kb+12] + f3.y*wa2[kb+13] + f3.z*wa2[kb+14] + f3.w*wa2[kb+15];
  };
  auto mfma_step = [&](int cb) {
    bf16x8 bfv[4];
#pragma unroll
    for (int fj = 0; fj < 4; ++fj)
      bfv[fj] = *(const bf16x8*)(Bb + ((cb * 4 + g16) * 256 + wc * 64 + fj * 16 + c15) * 8);
#pragma unroll
    for (int fi = 0; fi < 8; ++fi) {
      bf16x8 af = *(const bf16x8*)(Ab + ((cb * 4 + g16) * 256 + wr * 128 + fi * 16 + c15) * 8);
#pragma unroll
      for (int fj = 0; fj < 4; ++fj)
        acc[fi][fj] = __builtin_amdgcn_mfma_f32_16x16x32_bf16(
            af, bfv[fj], acc[fi][fj], 0, 0, 0);
    }
  };

  float4 xc0 = *(const float4*)(xsrc +  0);
  float4 xc1 = *(const float4*)(xsrc +  4);
  float4 xc2 = *(const float4*)(xsrc +  8);
  float4 xc3 = *(const float4*)(xsrc + 12);
  float4 xb0 = *(const float4*)(xsrc + 32);
  float4 xb1 = *(const float4*)(xsrc + 36);
  float4 xb2 = *(const float4*)(xsrc + 40);
  float4 xb3 = *(const float4*)(xsrc + 44);
  float4 xa0 = *(const float4*)(xsrc + 64);
  float4 xa1 = *(const float4*)(xsrc + 68);
  float4 xa2 = *(const float4*)(xsrc + 72);
  float4 xa3 = *(const float4*)(xsrc + 76);
  __syncthreads();                 // wa1/wa2 visible
  stage(0, 0, xc0, xc1, xc2, xc3);
  __syncthreads();                 // A[0] written, B[0] arrived
#pragma unroll 1
  for (int ks2 = 0; ks2 < 4; ++ks2) {
    stage(1, 2 * ks2 + 1, xb0, xb1, xb2, xb3);
    if (2 * ks2 + 3 < 8) {
      const float* s = xsrc + (2 * ks2 + 3) * 32;
      xb0 = *(const float4*)(s);      xb1 = *(const float4*)(s + 4);
      xb2 = *(const float4*)(s + 8);  xb3 = *(const float4*)(s + 12);
    }
    mfma_step(0);
    __syncthreads();
    if (2 * ks2 + 2 < 8) {
      stage(0, 2 * ks2 + 2, xa0, xa1, xa2, xa3);
      if (2 * ks2 + 4 < 8) {
        const float* s = xsrc + (2 * ks2 + 4) * 32;
        xa0 = *(const float4*)(s);      xa1 = *(const float4*)(s + 4);
        xa2 = *(const float4*)(s + 8);  xa3 = *(const float4*)(s + 12);
      }
    }
    mfma_step(1);
    __syncthreads();
  }
  // s1/s2: reduce 2 k-halves
  p1 += __shfl_xor(p1, 1, 64);
  p2 += __shfl_xor(p2, 1, 64);
  if (half == 0) { s1[rT + row] = p1; s2[rT + row] = p2; }
  // epilogue: row-major bf16 h via LDS repack (pitch 264 breaks conflicts)
  u16* ep = (u16*)smem;   // 64 x 264 u16 = 33792 B (smem free after last sync)
#pragma unroll 1
  for (int hh = 0; hh < 4; ++hh) {
    if (wr == (hh >> 1)) {
#pragma unroll
      for (int fi2 = 0; fi2 < 4; ++fi2) {
        const int fi = (hh & 1) * 4 + fi2;
        const int erow = fi2 * 16 + 4 * g16;
#pragma unroll
        for (int fj = 0; fj < 4; ++fj) {
          const int col = wc * 64 + fj * 16 + c15;
#pragma unroll
          for (int r = 0; r < 4; ++r) {
            __bf16 bv = (__bf16)acc[fi][fj][r];
            ep[(erow + r) * 264 + col] = __builtin_bit_cast(u16, bv);
          }
        }
      }
    }
    __syncthreads();
    const int rrow = t >> 3, seg = t & 7;
    const u16* src = ep + rrow * 264 + seg * 32;
    u16* dst = h + (size_t)(rT + hh * 64 + rrow) * FD + seg * 32;
#pragma unroll
    for (int q = 0; q < 4; ++q)
      *(uint4*)(dst + q * 8) = *(const uint4*)(src + q * 8);
    __syncthreads();
  }
}

// -------- k_sc: per-batch sort(s2) + prefix scans + threshold emit --------
__global__ __launch_bounds__(512) void k_sc(
    const u16* __restrict__ h, const float* __restrict__ s1,
    const float* __restrict__ s2, float* __restrict__ out) {
  __shared__ float key[1024];     // sorted s2
  __shared__ u16   pid[1024];     // jmap
  __shared__ float e2l[1024], e2al[1024];
  __shared__ float Su[1025], Sv[1025];
  __shared__ float c1l[1024], c2l[1024];
  __shared__ u32   cnt[1025];
  __shared__ u16   ibl[1025];
  __shared__ u16   iol[1024];
  __shared__ float UpS[8];
  __shared__ float Up[8][64], Vp[8][64];
  const int t = threadIdx.x;
  const int b = blockIdx.y, fc = blockIdx.x;
  const int w = t >> 6, lane = t & 63;

  // 1) fill
  key[t]       = s2[(size_t)b * NENT + t];       pid[t]       = (u16)t;
  key[t + 512] = s2[(size_t)b * NENT + t + 512]; pid[t + 512] = (u16)(t + 512);
  __syncthreads();
  // 2) bitonic sort ascending (wave-synchronous; barrier only when j>=64)
  for (int kk = 2; kk <= 1024; kk <<= 1) {
    for (int j = kk >> 1; j > 0; j >>= 1) {
      if (j >= 64) __syncthreads();
      else asm volatile("" ::: "memory");
      const int i  = ((t & ~(j - 1)) << 1) | (t & (j - 1));
      const int ix = i | j;
      const bool up = ((i & kk) == 0);
      float a = key[i], c = key[ix];
      u16 pa = pid[i], pc = pid[ix];
      const bool sw = up ? (a > c) : (a < c);
      if (sw) { key[i] = c; key[ix] = a; pid[i] = pc; pid[ix] = pa; }
    }
  }
  __syncthreads();
  // 3) exp arrays
  {
    float k0 = key[t], k1 = key[t + 512];
    e2l[t] = __expf(k0);        e2l[t + 512] = __expf(k1);
    e2al[t] = __expf(ALPHA * k0); e2al[t + 512] = __expf(ALPHA * k1);
  }
  __syncthreads();
  // 4) scans (exclusive + total): wave shfl-scan + 8-partial combine
  auto scanx = [&](const float* src, float* dst) {
    float a = src[2 * t], bb = src[2 * t + 1];
    float s = a + bb;
    float inc = s;
#pragma unroll
    for (int d = 1; d < 64; d <<= 1) {
      float o = __shfl_up(inc, d, 64);
      if (lane >= d) inc += o;
    }
    if (lane == 63) UpS[w] = inc;
    __syncthreads();
    float woff = 0.f;
#pragma unroll
    for (int w2 = 0; w2 < 8; ++w2) { float pv = UpS[w2]; if (w2 < w) woff += pv; }
    float P = woff + inc - s;
    dst[2 * t] = P; dst[2 * t + 1] = P + a;
    if (t == 511) dst[1024] = P + s;
    __syncthreads();
  };
  scanx(e2l, Su);
  scanx(e2al, Sv);
  // 5) per-i coefs + k_i  (2 i's per thread)
  const float s2max = key[1023];
  const float SuN = Su[1024], SvN = Sv[1024];
  int kfA, kfB;
  {
    // zero hist first (reused as cursor later)
    cnt[t] = 0; cnt[t + 512] = 0;
    if (t == 0) cnt[1024] = 0;
  }
  __syncthreads();
#pragma unroll
  for (int hi = 0; hi < 2; ++hi) {
    const int i = t + hi * 512;
    const float s1v = s1[(size_t)b * NENT + i];
    const float th = -s1v;
    int kf = 0;
#pragma unroll
    for (int d = 1024; d >= 1; d >>= 1)
      if (kf + d <= 1024 && key[kf + d - 1] < th) kf += d;
    const float qm = s1v + s2max;
    const float m = fmaxf(qm, ALPHA * qm);
    const float en1 = __expf(fminf(s1v - m, 80.f));
    const float en2 = __expf(fminf(ALPHA * s1v - m, 80.f));
    const float Z = en1 * (SuN - Su[kf]) + en2 * Sv[kf];
    const float rZ = 1.f / Z;
    c1l[i] = en1 * rZ; c2l[i] = en2 * rZ;
    if (hi == 0) kfA = kf; else kfB = kf;
    atomicAdd(&cnt[kf], 1u);
  }
  __syncthreads();
  // 6) exclusive scan of cnt[0..1023] -> ibl[0..1024]; zero cnt for cursors
  {
    float a = (float)cnt[2 * t], bb = (float)cnt[2 * t + 1];
    cnt[2 * t] = 0; cnt[2 * t + 1] = 0;
    if (t == 0) cnt[1024] = 0;          // FIX: reset bucket-1024 cursor too
    float s = a + bb;
    float inc = s;
#pragma unroll
    for (int d = 1; d < 64; d <<= 1) {
      float o = __shfl_up(inc, d, 64);
      if (lane >= d) inc += o;
    }
    if (lane == 63) UpS[w] = inc;
    __syncthreads();
    float woff = 0.f;
#pragma unroll
    for (int w2 = 0; w2 < 8; ++w2) { float pv = UpS[w2]; if (w2 < w) woff += pv; }
    float P = woff + inc - s;
    ibl[2 * t] = (u16)P; ibl[2 * t + 1] = (u16)(P + a);
    if (t == 511) ibl[1024] = (u16)(P + s);
  }
  __syncthreads();
  // 7) scatter: iol = i's bucketed by k_i (CSR order); clamp defensively
  {
    int pos = (int)ibl[kfA] + (int)atomicAdd(&cnt[kfA], 1u);
    pos = pos < 1023 ? pos : 1023;
    iol[pos] = (u16)t;
    int posB = (int)ibl[kfB] + (int)atomicAdd(&cnt[kfB], 1u);
    posB = posB < 1023 ? posB : 1023;
    iol[posB] = (u16)(t + 512);
  }
  __syncthreads();
  // 8) sweeps: wave w owns sorted range [128w, 128w+128)
  const int col = fc * 64 + lane;
  const u16* hb = h + (size_t)b * NENT * FD + col;
  const int r0 = w * 128;
  float ha[8], hc[8];
  auto ldg8 = [&](float* dstv, int rbase) {
#pragma unroll
    for (int u = 0; u < 8; ++u) {
      u16 raw = hb[(size_t)((int)pid[rbase + u]) * FD];
      dstv[u] = (float)__builtin_bit_cast(__bf16, raw);
    }
  };
  float U = 0.f, V = 0.f;
  ldg8(ha, r0);
#pragma unroll 1
  for (int g = 0; g < 8; ++g) {
    const int rb = r0 + g * 16;
    ldg8(hc, rb + 8);
#pragma unroll
    for (int u = 0; u < 8; ++u) {
      U += e2l[rb + u] * ha[u]; V += e2al[rb + u] * ha[u];
    }
    if (g < 7) ldg8(ha, rb + 16);
#pragma unroll
    for (int u = 0; u < 8; ++u) {
      U += e2l[rb + 8 + u] * hc[u]; V += e2al[rb + 8 + u] * hc[u];
    }
  }
  Up[w][lane] = U; Vp[w][lane] = V;
  __syncthreads();
  float Uoff = 0.f, Voff = 0.f, UN = 0.f, VN = 0.f;
#pragma unroll
  for (int w2 = 0; w2 < 8; ++w2) {
    float a = Up[w2][lane], c = Vp[w2][lane];
    if (w2 < w) { Uoff += a; Voff += c; }
    UN += a; VN += c;
  }
  // sweep 2: running U,V + emissions at bucket boundaries
  U = Uoff; V = Voff;
  ldg8(ha, r0);
#pragma unroll 1
  for (int g = 0; g < 8; ++g) {
    const int rb = r0 + g * 16;
    ldg8(hc, rb + 8);
#pragma unroll
    for (int u = 0; u < 8; ++u) {
      const int r = rb + u;
      const int e0 = ibl[r], e1 = ibl[r + 1];
      for (int idx = e0; idx < e1; ++idx) {
        const int i = iol[idx];
        out[((size_t)b * NENT + i) * FD + col] = c1l[i] * (UN - U) + c2l[i] * V;
      }
      U += e2l[r] * ha[u]; V += e2al[r] * ha[u];
    }
    if (g < 7) ldg8(ha, rb + 16);
#pragma unroll
    for (int u = 0; u < 8; ++u) {
      const int r = rb + 8 + u;
      const int e0 = ibl[r], e1 = ibl[r + 1];
      for (int idx = e0; idx < e1; ++idx) {
        const int i = iol[idx];
        out[((size_t)b * NENT + i) * FD + col] = c1l[i] * (UN - U) + c2l[i] * V;
      }
      U += e2l[r] * hc[u]; V += e2al[r] * hc[u];
    }
  }
  if (w == 7) {           // k_i == 1024 bucket: U==UN, V==VN here
    const int e0 = ibl[1024];
    for (int idx = e0; idx < 1024; ++idx) {
      const int i = iol[idx];
      out[((size_t)b * NENT + i) * FD + col] = c1l[i] * (UN - U) + c2l[i] * V;
    }
  }
}

extern "C" void kernel_launch(void* const* d_in, const int* in_sizes, int n_in,
                              void* d_out, int out_size, void* d_ws, size_t ws_size,
                              hipStream_t stream) {
  const float* x = (const float*)d_in[0];
  const float* W = (const float*)d_in[1];
  const float* a = (const float*)d_in[2];
  float* out = (float*)d_out;

  char* ws = (char*)d_ws;
  u16*   h   = (u16*)ws;                         // 33,554,432 B
  float* s1  = (float*)(ws + (size_t)33554432);  // 256 KB
  float* s2  = s1 + NROWS;                       // 256 KB
  float* Wa1 = s2 + NROWS;                       // 1 KB
  float* Wa2 = Wa1 + FD;                         // 1 KB
  u16*   Wt  = (u16*)(Wa2 + FD);                 // 128 KB   (~34.2 MB total)

  k_wa<<<dim3(256), dim3(256), 0, stream>>>(W, a, Wa1, Wa2);
  k_wt<<<dim3(16), dim3(256), 0, stream>>>(W, Wt);
  k_h<<<dim3(256), dim3(512), 0, stream>>>(x, Wt, Wa1, Wa2, h, s1, s2);
  k_sc<<<dim3(4, NB), dim3(512), 0, stream>>>(h, s1, s2, out);
}

// Round 7
// 93.444 us; speedup vs baseline: 2.0555x; 2.0555x over previous
//
#include <hip/hip_runtime.h>

// GAT, round 6: (1) k_h epilogue made fully static (R6's runtime acc index
// demoted acc[8][4] to scratch -> 624 MB HBM writes, 5x regression);
// (2) k_sc LDS-op diet: u64-packed bitonic sort, vectorized pid/e2l/e2al/ibl
// reads in the sweeps.
// Algorithm: e_ij = leaky(s1_i + s2_j) rank-1 + monotone kink; sort j by s2,
// negative branch is a prefix per row:
//   out_i = c1_i*(U_N - U_{k_i}) + c2_i*V_{k_i};  O(N^2 F) -> O(N F).

typedef unsigned short u16;
typedef unsigned int   u32;
typedef unsigned long long u64;
typedef float  f32x4  __attribute__((ext_vector_type(4)));
typedef __bf16 bf16x8 __attribute__((ext_vector_type(8)));
typedef __bf16 bf16x4 __attribute__((ext_vector_type(4)));

#define NB    64
#define NENT  1024
#define FD    256
#define NROWS (NB * NENT)
#define ALPHA 0.2f

typedef __attribute__((address_space(1))) const void* gas_ptr;
typedef __attribute__((address_space(3))) void*       las_ptr;
__device__ __forceinline__ void gload16(const void* g, void* l) {
  __builtin_amdgcn_global_load_lds((gas_ptr)g, (las_ptr)l, 16, 0, 0);
}

// ---------------- k_wa: Wa1 = W@a1, Wa2 = W@a2 (fp32 exact) ----------------
__global__ __launch_bounds__(256) void k_wa(const float* __restrict__ W,
                                            const float* __restrict__ a,
                                            float* __restrict__ Wa1,
                                            float* __restrict__ Wa2) {
  const int k = blockIdx.x, f = threadIdx.x;
  const float w = W[(size_t)k * FD + f];
  float p1 = w * a[f];
  float p2 = w * a[FD + f];
#pragma unroll
  for (int off = 1; off < 64; off <<= 1) {
    p1 += __shfl_xor(p1, off, 64);
    p2 += __shfl_xor(p2, off, 64);
  }
  __shared__ float r1[4], r2[4];
  const int wv = f >> 6, lane = f & 63;
  if (lane == 0) { r1[wv] = p1; r2[wv] = p2; }
  __syncthreads();
  if (f == 0) {
    Wa1[k] = r1[0] + r1[1] + r1[2] + r1[3];
    Wa2[k] = r2[0] + r2[1] + r2[2] + r2[3];
  }
}

// ---------------- k_wt: Wt[f][k] = bf16(W[k][f]) ----------------
__global__ __launch_bounds__(256) void k_wt(const float* __restrict__ W,
                                            u16* __restrict__ Wt) {
  __shared__ float tile[64][65];
  const int t = threadIdx.x;
  const int ki = blockIdx.x >> 2, fi = blockIdx.x & 3;
  const int k0 = ki * 64, f0 = fi * 64;
  const int r = t >> 4, c4 = (t & 15) * 4;
#pragma unroll
  for (int it = 0; it < 4; ++it) {
    const int row = r + it * 16;
    float4 v = *(const float4*)&W[(size_t)(k0 + row) * FD + f0 + c4];
    tile[row][c4 + 0] = v.x; tile[row][c4 + 1] = v.y;
    tile[row][c4 + 2] = v.z; tile[row][c4 + 3] = v.w;
  }
  __syncthreads();
#pragma unroll
  for (int it = 0; it < 4; ++it) {
    const int fr = r + it * 16;
    bf16x4 pk;
    pk[0] = (__bf16)tile[c4 + 0][fr]; pk[1] = (__bf16)tile[c4 + 1][fr];
    pk[2] = (__bf16)tile[c4 + 2][fr]; pk[3] = (__bf16)tile[c4 + 3][fr];
    *(bf16x4*)&Wt[(size_t)(f0 + fr) * FD + k0 + c4] = pk;
  }
}

// -------- k_h: h = bf16(x@W) row-major, s1, s2 (256x256 tile, dbuf) --------
__global__ __launch_bounds__(512, 2) void k_h(
    const float* __restrict__ x, const u16* __restrict__ Wt,
    const float* __restrict__ Wa1g, const float* __restrict__ Wa2g,
    u16* __restrict__ h, float* __restrict__ s1, float* __restrict__ s2) {
  __shared__ __align__(16) char smem[67584];
  u16* Ab = (u16*)smem;                    // [2][4][256][8] = 32 KB
  u16* Bb = (u16*)(smem + 32768);          // [2][4][256][8] = 32 KB
  float* wa1 = (float*)(smem + 65536);
  float* wa2 = wa1 + FD;
  const int t = threadIdx.x;
  const int lane = t & 63, wv = t >> 6;
  const int wr = wv >> 2, wc = wv & 3;          // wave tile 128x64
  const int g16 = lane >> 4, c15 = lane & 15;
  const int p = blockIdx.x;
  const int lb = (p & 7) * 32 + (p >> 3);       // XCD-chunked
  const int rT = lb * 256;
  if (t < FD) { wa1[t] = Wa1g[t]; wa2[t] = Wa2g[t]; }
  const int row = t >> 1, half = t & 1;         // staging: 2 thr/row, 16 k
  const float* xsrc = x + (size_t)(rT + row) * FD + half * 16;
  float p1 = 0.f, p2 = 0.f;
  f32x4 acc[8][4];
  const f32x4 vz = {0.f, 0.f, 0.f, 0.f};
#pragma unroll
  for (int i = 0; i < 8; ++i)
#pragma unroll
    for (int j = 0; j < 4; ++j) acc[i][j] = vz;

  auto stage = [&](int nb, int kc, const float4& f0, const float4& f1,
                   const float4& f2, const float4& f3) {
    const int k0n = kc * 32;
    const int d0 = t;
    gload16(Wt + (size_t)(d0 & 255) * FD + k0n + (d0 >> 8) * 8,
            (char*)Bb + nb * 8192 * 2 + d0 * 16);
    const int d1 = t + 512;
    gload16(Wt + (size_t)(d1 & 255) * FD + k0n + (d1 >> 8) * 8,
            (char*)Bb + nb * 8192 * 2 + d1 * 16);
    bf16x8 w0, w1;
    w0[0] = (__bf16)f0.x; w0[1] = (__bf16)f0.y;
    w0[2] = (__bf16)f0.z; w0[3] = (__bf16)f0.w;
    w0[4] = (__bf16)f1.x; w0[5] = (__bf16)f1.y;
    w0[6] = (__bf16)f1.z; w0[7] = (__bf16)f1.w;
    w1[0] = (__bf16)f2.x; w1[1] = (__bf16)f2.y;
    w1[2] = (__bf16)f2.z; w1[3] = (__bf16)f2.w;
    w1[4] = (__bf16)f3.x; w1[5] = (__bf16)f3.y;
    w1[6] = (__bf16)f3.z; w1[7] = (__bf16)f3.w;
    *(bf16x8*)(Ab + ((nb * 4 + half * 2) * 256 + row) * 8) = w0;
    *(bf16x8*)(Ab + ((nb * 4 + half * 2 + 1) * 256 + row) * 8) = w1;
    const int kb = k0n + half * 16;
    p1 += f0.x*wa1[kb+ 0] + f0.y*wa1[kb+ 1] + f0.z*wa1[kb+ 2] + f0.w*wa1[kb+ 3]
        + f1.x*wa1[kb+ 4] + f1.y*wa1[kb+ 5] + f1.z*wa1[kb+ 6] + f1.w*wa1[kb+ 7]
        + f2.x*wa1[kb+ 8] + f2.y*wa1[kb+ 9] + f2.z*wa1[kb+10] + f2.w*wa1[kb+11]
        + f3.x*wa1[kb+12] + f3.y*wa1[kb+13] + f3.z*wa1[kb+14] + f3.w*wa1[kb+15];
    p2 += f0.x*wa2[kb+ 0] + f0.y*wa2[kb+ 1] + f0.z*wa2[kb+ 2] + f0.w*wa2[kb+ 3]
        + f1.x*wa2[kb+ 4] + f1.y*wa2[kb+ 5] + f1.z*wa2[kb+ 6] + f1.w*wa2[kb+ 7]
        + f2.x*wa2[kb+ 8] + f2.y*wa2[kb+ 9] + f2.z*wa2[kb+10] + f2.w*wa2[kb+11]
        + f3.x*wa2[kb+12] + f3.y*wa2[kb+13] + f3.z*wa2[kb+14] + f3.w*wa2[kb+15];
  };
  auto mfma_step = [&](int cb) {
    bf16x8 bfv[4];
#pragma unroll
    for (int fj = 0; fj < 4; ++fj)
      bfv[fj] = *(const bf16x8*)(Bb + ((cb * 4 + g16) * 256 + wc * 64 + fj * 16 + c15) * 8);
#pragma unroll
    for (int fi = 0; fi < 8; ++fi) {
      bf16x8 af = *(const bf16x8*)(Ab + ((cb * 4 + g16) * 256 + wr * 128 + fi * 16 + c15) * 8);
#pragma unroll
      for (int fj = 0; fj < 4; ++fj)
        acc[fi][fj] = __builtin_amdgcn_mfma_f32_16x16x32_bf16(
            af, bfv[fj], acc[fi][fj], 0, 0, 0);
    }
  };

  float4 xc0 = *(const float4*)(xsrc +  0);
  float4 xc1 = *(const float4*)(xsrc +  4);
  float4 xc2 = *(const float4*)(xsrc +  8);
  float4 xc3 = *(const float4*)(xsrc + 12);
  float4 xb0 = *(const float4*)(xsrc + 32);
  float4 xb1 = *(const float4*)(xsrc + 36);
  float4 xb2 = *(const float4*)(xsrc + 40);
  float4 xb3 = *(const float4*)(xsrc + 44);
  float4 xa0 = *(const float4*)(xsrc + 64);
  float4 xa1 = *(const float4*)(xsrc + 68);
  float4 xa2 = *(const float4*)(xsrc + 72);
  float4 xa3 = *(const float4*)(xsrc + 76);
  __syncthreads();                 // wa1/wa2 visible
  stage(0, 0, xc0, xc1, xc2, xc3);
  __syncthreads();                 // A[0] written, B[0] arrived
#pragma unroll 1
  for (int ks2 = 0; ks2 < 4; ++ks2) {
    stage(1, 2 * ks2 + 1, xb0, xb1, xb2, xb3);
    if (2 * ks2 + 3 < 8) {
      const float* s = xsrc + (2 * ks2 + 3) * 32;
      xb0 = *(const float4*)(s);      xb1 = *(const float4*)(s + 4);
      xb2 = *(const float4*)(s + 8);  xb3 = *(const float4*)(s + 12);
    }
    mfma_step(0);
    __syncthreads();
    if (2 * ks2 + 2 < 8) {
      stage(0, 2 * ks2 + 2, xa0, xa1, xa2, xa3);
      if (2 * ks2 + 4 < 8) {
        const float* s = xsrc + (2 * ks2 + 4) * 32;
        xa0 = *(const float4*)(s);      xa1 = *(const float4*)(s + 4);
        xa2 = *(const float4*)(s + 8);  xa3 = *(const float4*)(s + 12);
      }
    }
    mfma_step(1);
    __syncthreads();
  }
  // s1/s2: reduce 2 k-halves
  p1 += __shfl_xor(p1, 1, 64);
  p2 += __shfl_xor(p2, 1, 64);
  if (half == 0) { s1[rT + row] = p1; s2[rT + row] = p2; }
  // epilogue: row-major bf16 h via LDS repack. FULLY UNROLLED so every acc
  // index is compile-time (rule #20: runtime index -> scratch demotion).
  u16* ep = (u16*)smem;   // 64 x 264 u16 = 33792 B
#pragma unroll
  for (int hh = 0; hh < 4; ++hh) {
    if (wr == (hh >> 1)) {
#pragma unroll
      for (int fi2 = 0; fi2 < 4; ++fi2) {
        const int erow = fi2 * 16 + 4 * g16;
#pragma unroll
        for (int fj = 0; fj < 4; ++fj) {
          const int col = wc * 64 + fj * 16 + c15;
#pragma unroll
          for (int r = 0; r < 4; ++r) {
            __bf16 bv = (__bf16)acc[(hh & 1) * 4 + fi2][fj][r];
            ep[(erow + r) * 264 + col] = __builtin_bit_cast(u16, bv);
          }
        }
      }
    }
    __syncthreads();
    const int rrow = t >> 3, seg = t & 7;
    const u16* src = ep + rrow * 264 + seg * 32;
    u16* dst = h + (size_t)(rT + hh * 64 + rrow) * FD + seg * 32;
#pragma unroll
    for (int q = 0; q < 4; ++q)
      *(uint4*)(dst + q * 8) = *(const uint4*)(src + q * 8);
    __syncthreads();
  }
}

// -------- k_sc: per-batch sort(s2) + prefix scans + threshold emit --------
__global__ __launch_bounds__(512) void k_sc(
    const u16* __restrict__ h, const float* __restrict__ s1,
    const float* __restrict__ s2, float* __restrict__ out) {
  __shared__ __align__(16) u64  kp[1024];       // packed (sortable-key, j)
  __shared__ __align__(16) float key[1024];
  __shared__ __align__(16) u16   pid[1024];
  __shared__ __align__(16) float e2l[1024], e2al[1024];
  __shared__ __align__(16) float Su[1032], Sv[1032];
  __shared__ __align__(16) float c1l[1024], c2l[1024];
  __shared__ __align__(16) u32   cnt[1025];
  __shared__ __align__(16) u16   ibl[1032];
  __shared__ __align__(16) u16   iol[1024];
  __shared__ float UpS[8];
  __shared__ float Up[8][64], Vp[8][64];
  const int t = threadIdx.x;
  const int b = blockIdx.y, fc = blockIdx.x;
  const int w = t >> 6, lane = t & 63;

  // 1) fill packed sort keys: monotone f32->u32 map, j in low bits
  auto packkey = [&](int j) {
    float v = s2[(size_t)b * NENT + j];
    u32 u = __builtin_bit_cast(u32, v);
    u32 su = u ^ (u32)(((int)u >> 31) | 0x80000000);
    kp[j] = ((u64)su << 32) | (u32)j;
  };
  packkey(t); packkey(t + 512);
  __syncthreads();
  // 2) bitonic sort ascending on u64 (wave-synchronous below j=64)
#pragma unroll 1
  for (int kk = 2; kk <= 1024; kk <<= 1) {
#pragma unroll 1
    for (int j = kk >> 1; j > 0; j >>= 1) {
      if (j >= 64) __syncthreads();
      else asm volatile("" ::: "memory");
      const int i  = ((t & ~(j - 1)) << 1) | (t & (j - 1));
      const int ix = i | j;
      const bool up = ((i & kk) == 0);
      u64 a = kp[i], c = kp[ix];
      const bool sw = up ? (a > c) : (a < c);
      if (sw) { kp[i] = c; kp[ix] = a; }
    }
  }
  __syncthreads();
  // 3) unpack + exp arrays
  auto unpack = [&](int r) {
    u64 v = kp[r];
    u32 su = (u32)(v >> 32);
    u32 ub = (su & 0x80000000u) ? (su ^ 0x80000000u) : ~su;
    float kv = __builtin_bit_cast(float, ub);
    key[r] = kv;
    pid[r] = (u16)(v & 0xFFFFu);
    e2l[r] = __expf(kv);
    e2al[r] = __expf(ALPHA * kv);
  };
  unpack(t); unpack(t + 512);
  __syncthreads();
  // 4) scans (exclusive + total)
  auto scanx = [&](const float* src, float* dst) {
    float a = src[2 * t], bb = src[2 * t + 1];
    float s = a + bb;
    float inc = s;
#pragma unroll
    for (int d = 1; d < 64; d <<= 1) {
      float o = __shfl_up(inc, d, 64);
      if (lane >= d) inc += o;
    }
    if (lane == 63) UpS[w] = inc;
    __syncthreads();
    float woff = 0.f;
#pragma unroll
    for (int w2 = 0; w2 < 8; ++w2) { float pv = UpS[w2]; if (w2 < w) woff += pv; }
    float P = woff + inc - s;
    dst[2 * t] = P; dst[2 * t + 1] = P + a;
    if (t == 511) dst[1024] = P + s;
    __syncthreads();
  };
  scanx(e2l, Su);
  scanx(e2al, Sv);
  // 5) per-i coefs + k_i (2 i's per thread)
  const float s2max = key[1023];
  const float SuN = Su[1024];
  int kfA, kfB;
  cnt[t] = 0; cnt[t + 512] = 0;
  if (t == 0) cnt[1024] = 0;
  __syncthreads();
#pragma unroll
  for (int hi = 0; hi < 2; ++hi) {
    const int i = t + hi * 512;
    const float s1v = s1[(size_t)b * NENT + i];
    const float th = -s1v;
    int kf = 0;
#pragma unroll
    for (int d = 1024; d >= 1; d >>= 1)
      if (kf + d <= 1024 && key[kf + d - 1] < th) kf += d;
    const float qm = s1v + s2max;
    const float m = fmaxf(qm, ALPHA * qm);
    const float en1 = __expf(fminf(s1v - m, 80.f));
    const float en2 = __expf(fminf(ALPHA * s1v - m, 80.f));
    const float Z = en1 * (SuN - Su[kf]) + en2 * Sv[kf];
    const float rZ = 1.f / Z;
    c1l[i] = en1 * rZ; c2l[i] = en2 * rZ;
    if (hi == 0) kfA = kf; else kfB = kf;
    atomicAdd(&cnt[kf], 1u);
  }
  __syncthreads();
  // 6) exclusive scan of cnt -> ibl; zero cnt for cursors (incl bucket 1024)
  {
    float a = (float)cnt[2 * t], bb = (float)cnt[2 * t + 1];
    cnt[2 * t] = 0; cnt[2 * t + 1] = 0;
    if (t == 0) cnt[1024] = 0;
    float s = a + bb;
    float inc = s;
#pragma unroll
    for (int d = 1; d < 64; d <<= 1) {
      float o = __shfl_up(inc, d, 64);
      if (lane >= d) inc += o;
    }
    if (lane == 63) UpS[w] = inc;
    __syncthreads();
    float woff = 0.f;
#pragma unroll
    for (int w2 = 0; w2 < 8; ++w2) { float pv = UpS[w2]; if (w2 < w) woff += pv; }
    float P = woff + inc - s;
    ibl[2 * t] = (u16)P; ibl[2 * t + 1] = (u16)(P + a);
    if (t == 511) ibl[1024] = (u16)(P + s);
  }
  __syncthreads();
  // 7) scatter i's bucketed by k_i (CSR); defensive clamp
  {
    int pos = (int)ibl[kfA] + (int)atomicAdd(&cnt[kfA], 1u);
    pos = pos < 1023 ? pos : 1023;
    iol[pos] = (u16)t;
    int posB = (int)ibl[kfB] + (int)atomicAdd(&cnt[kfB], 1u);
    posB = posB < 1023 ? posB : 1023;
    iol[posB] = (u16)(t + 512);
  }
  __syncthreads();
  // 8) sweeps: wave w owns sorted range [128w, 128w+128)
  const int col = fc * 64 + lane;
  const u16* hb = h + (size_t)b * NENT * FD + col;
  const int r0 = w * 128;
  float ha[8], hc[8];
  auto ldh8 = [&](float* dv, int rb) {          // 1 vec pid read + 8 gathers
    uint4 praw = *(const uint4*)&pid[rb];
    const u16* pp = (const u16*)&praw;
#pragma unroll
    for (int u2 = 0; u2 < 8; ++u2) {
      u32 raw = hb[(size_t)pp[u2] * FD];
      dv[u2] = __builtin_bit_cast(float, raw << 16);
    }
  };
  auto lde8 = [&](float* E, float* A2, int rb) {  // vectorized e2l/e2al
    *(float4*)&E[0]  = *(const float4*)&e2l[rb];
    *(float4*)&E[4]  = *(const float4*)&e2l[rb + 4];
    *(float4*)&A2[0] = *(const float4*)&e2al[rb];
    *(float4*)&A2[4] = *(const float4*)&e2al[rb + 4];
  };
  float U = 0.f, V = 0.f;
  ldh8(ha, r0);
#pragma unroll 1
  for (int g = 0; g < 8; ++g) {
    const int rb = r0 + g * 16;
    ldh8(hc, rb + 8);
    float E[8], A2[8];
    lde8(E, A2, rb);
#pragma unroll
    for (int u2 = 0; u2 < 8; ++u2) { U += E[u2] * ha[u2]; V += A2[u2] * ha[u2]; }
    if (g < 7) ldh8(ha, rb + 16);
    lde8(E, A2, rb + 8);
#pragma unroll
    for (int u2 = 0; u2 < 8; ++u2) { U += E[u2] * hc[u2]; V += A2[u2] * hc[u2]; }
  }
  Up[w][lane] = U; Vp[w][lane] = V;
  __syncthreads();
  float Uoff = 0.f, Voff = 0.f, UN = 0.f, VN = 0.f;
#pragma unroll
  for (int w2 = 0; w2 < 8; ++w2) {
    float a = Up[w2][lane], c = Vp[w2][lane];
    if (w2 < w) { Uoff += a; Voff += c; }
    UN += a; VN += c;
  }
  // sweep 2: running U,V + emissions at bucket boundaries
  U = Uoff; V = Voff;
  ldh8(ha, r0);
#pragma unroll 1
  for (int g = 0; g < 8; ++g) {
    const int rb = r0 + g * 16;
    ldh8(hc, rb + 8);
    float E[8], A2[8];
    lde8(E, A2, rb);
    uint4 ibraw = *(const uint4*)&ibl[rb];
    const u16* ib = (const u16*)&ibraw;
    u16 ibn = ibl[rb + 8];
#pragma unroll
    for (int u2 = 0; u2 < 8; ++u2) {
      const int e0 = ib[u2], e1 = (u2 < 7) ? ib[u2 + 1] : (int)ibn;
      for (int idx = e0; idx < e1; ++idx) {
        const int i = iol[idx];
        out[((size_t)b * NENT + i) * FD + col] = c1l[i] * (UN - U) + c2l[i] * V;
      }
      U += E[u2] * ha[u2]; V += A2[u2] * ha[u2];
    }
    if (g < 7) ldh8(ha, rb + 16);
    lde8(E, A2, rb + 8);
    uint4 ibraw2 = *(const uint4*)&ibl[rb + 8];
    const u16* ib2 = (const u16*)&ibraw2;
    u16 ibn2 = ibl[rb + 16];
#pragma unroll
    for (int u2 = 0; u2 < 8; ++u2) {
      const int e0 = ib2[u2], e1 = (u2 < 7) ? ib2[u2 + 1] : (int)ibn2;
      for (int idx = e0; idx < e1; ++idx) {
        const int i = iol[idx];
        out[((size_t)b * NENT + i) * FD + col] = c1l[i] * (UN - U) + c2l[i] * V;
      }
      U += E[u2] * hc[u2]; V += A2[u2] * hc[u2];
    }
  }
  if (w == 7) {           // k_i == 1024 bucket (U==UN, V==VN here)
    const int e0 = ibl[1024];
    for (int idx = e0; idx < 1024; ++idx) {
      const int i = iol[idx];
      out[((size_t)b * NENT + i) * FD + col] = c1l[i] * (UN - U) + c2l[i] * V;
    }
  }
}

extern "C" void kernel_launch(void* const* d_in, const int* in_sizes, int n_in,
                              void* d_out, int out_size, void* d_ws, size_t ws_size,
                              hipStream_t stream) {
  const float* x = (const float*)d_in[0];
  const float* W = (const float*)d_in[1];
  const float* a = (const float*)d_in[2];
  float* out = (float*)d_out;

  char* ws = (char*)d_ws;
  u16*   h   = (u16*)ws;                         // 32 MB
  float* s1  = (float*)(ws + (size_t)33554432);  // 256 KB
  float* s2  = s1 + NROWS;                       // 256 KB
  float* Wa1 = s2 + NROWS;                       // 1 KB
  float* Wa2 = Wa1 + FD;                         // 1 KB
  u16*   Wt  = (u16*)(Wa2 + FD);                 // 128 KB

  k_wa<<<dim3(256), dim3(256), 0, stream>>>(W, a, Wa1, Wa2);
  k_wt<<<dim3(16), dim3(256), 0, stream>>>(W, Wt);
  k_h<<<dim3(256), dim3(512), 0, stream>>>(x, Wt, Wa1, Wa2, h, s1, s2);
  k_sc<<<dim3(4, NB), dim3(512), 0, stream>>>(h, s1, s2, out);
}